// Round 1
// baseline (391.243 us; speedup 1.0000x reference)
//
#include <hip/hip_runtime.h>
#include <hip/hip_bf16.h>

#define DIM 512
#define NROWS 1024
#define NCLS 70722
#define BK 32
#define LDT 40   // 32 + 8 pad (keeps 16B alignment, 2-way bank conflicts only)

typedef float  floatx4 __attribute__((ext_vector_type(4)));
typedef short  shortx8 __attribute__((ext_vector_type(8)));

__device__ __forceinline__ unsigned short f2bf(float f) {
    union { float f; unsigned int u; } v; v.f = f;
    unsigned int r = v.u + 0x7FFFu + ((v.u >> 16) & 1u);  // RNE
    return (unsigned short)(r >> 16);
}

__device__ __forceinline__ float wave_reduce_sum(float s) {
    #pragma unroll
    for (int m = 1; m < 64; m <<= 1) s += __shfl_xor(s, m);
    return s;
}

// --- kernel 1: per-row x norms + normalized bf16 x -------------------------
__global__ __launch_bounds__(256) void prep_x_kernel(
        const float* __restrict__ x, unsigned short* __restrict__ normx,
        float* __restrict__ rownorm) {
    int wv = threadIdx.x >> 6, lane = threadIdx.x & 63;
    int row = blockIdx.x * 4 + wv;
    const float4* src = (const float4*)(x + row * DIM);
    float4 a = src[lane], b = src[lane + 64];
    float ss = a.x*a.x + a.y*a.y + a.z*a.z + a.w*a.w
             + b.x*b.x + b.y*b.y + b.z*b.z + b.w*b.w;
    ss = wave_reduce_sum(ss);
    float norm = sqrtf(ss);
    float inv  = 1.0f / fmaxf(norm, 1e-12f);
    ushort4 o0; o0.x = f2bf(a.x*inv); o0.y = f2bf(a.y*inv); o0.z = f2bf(a.z*inv); o0.w = f2bf(a.w*inv);
    ushort4 o1; o1.x = f2bf(b.x*inv); o1.y = f2bf(b.y*inv); o1.z = f2bf(b.z*inv); o1.w = f2bf(b.w*inv);
    ((ushort4*)(normx + row * DIM))[lane]      = o0;
    ((ushort4*)(normx + row * DIM))[lane + 64] = o1;
    if (lane == 0) rownorm[row] = norm;
}

// --- kernel 2: batch stats -> per-row margins ------------------------------
__global__ __launch_bounds__(1024) void stats_kernel(
        const float* __restrict__ rownorm,
        float* __restrict__ g_ang, float* __restrict__ g_add) {
    __shared__ float sd[1024];
    int t = threadIdx.x;
    float v = fminf(fmaxf(rownorm[t], 0.001f), 100.0f);   // safe_norms
    sd[t] = v; __syncthreads();
    for (int s = 512; s > 0; s >>= 1) { if (t < s) sd[t] += sd[t + s]; __syncthreads(); }
    float mean = sd[0] * (1.0f / 1024.0f);
    __syncthreads();
    float d = v - mean;
    sd[t] = d * d; __syncthreads();
    for (int s = 512; s > 0; s >>= 1) { if (t < s) sd[t] += sd[t + s]; __syncthreads(); }
    float stdv = sqrtf(sd[0] * (1.0f / 1023.0f));         // ddof=1
    float ms = d / (stdv + 0.001f) * 0.333f;
    ms = fminf(fmaxf(ms, -1.0f), 1.0f);
    g_ang[t] = -0.4f * ms;
    g_add[t] =  0.4f + 0.4f * ms;
}

// --- kernel 3: per-class 1/||w|| -------------------------------------------
__global__ __launch_bounds__(256) void prep_w_kernel(
        const float* __restrict__ W, float* __restrict__ invn) {
    int wv = threadIdx.x >> 6, lane = threadIdx.x & 63;
    int c = blockIdx.x * 4 + wv;
    if (c >= NCLS) return;
    const float4* src = (const float4*)(W + (size_t)c * DIM);
    float4 a = src[lane], b = src[lane + 64];
    float ss = a.x*a.x + a.y*a.y + a.z*a.z + a.w*a.w
             + b.x*b.x + b.y*b.y + b.z*b.z + b.w*b.w;
    ss = wave_reduce_sum(ss);
    if (lane == 0) invn[c] = 1.0f / fmaxf(sqrtf(ss), 1e-12f);
}

// --- kernel 4: fused GEMM + sum(exp(64c - 64)) per row ---------------------
__global__ __launch_bounds__(256) void gemm_kernel(
        const unsigned short* __restrict__ normx, const float* __restrict__ W,
        const float* __restrict__ invn, float* __restrict__ rowsum) {
    __shared__ unsigned short As[128 * LDT];
    __shared__ unsigned short Bs[128 * LDT];
    __shared__ float red[128];
    int t = threadIdx.x, lane = t & 63, wv = t >> 6;
    int mtile = blockIdx.x, ctile = blockIdx.y;

    int rowA = t >> 1, half = t & 1;
    const unsigned short* aSrc = normx + (mtile * 128 + rowA) * DIM + half * 16;
    int cls = min(ctile * 128 + rowA, NCLS - 1);
    const float* bSrc = W + (size_t)cls * DIM + half * 16;
    float scale = invn[cls];
    unsigned short* aDst = As + rowA * LDT + half * 16;
    unsigned short* bDst = Bs + rowA * LDT + half * 16;
    if (t < 128) red[t] = 0.0f;

    floatx4 acc[4][4] = {};
    int wm = (wv >> 1) * 64, wn = (wv & 1) * 64;
    int fr = lane & 15, fq = lane >> 4;

    for (int kc = 0; kc < DIM; kc += BK) {
        uint4  a0 = *(const uint4*)(aSrc + kc);
        uint4  a1 = *(const uint4*)(aSrc + kc + 8);
        float4 b0 = *(const float4*)(bSrc + kc);
        float4 b1 = *(const float4*)(bSrc + kc + 4);
        float4 b2 = *(const float4*)(bSrc + kc + 8);
        float4 b3 = *(const float4*)(bSrc + kc + 12);
        __syncthreads();
        *(uint4*)(aDst)     = a0;
        *(uint4*)(aDst + 8) = a1;
        ushort4 p0; p0.x=f2bf(b0.x*scale); p0.y=f2bf(b0.y*scale); p0.z=f2bf(b0.z*scale); p0.w=f2bf(b0.w*scale);
        ushort4 p1; p1.x=f2bf(b1.x*scale); p1.y=f2bf(b1.y*scale); p1.z=f2bf(b1.z*scale); p1.w=f2bf(b1.w*scale);
        ushort4 p2; p2.x=f2bf(b2.x*scale); p2.y=f2bf(b2.y*scale); p2.z=f2bf(b2.z*scale); p2.w=f2bf(b2.w*scale);
        ushort4 p3; p3.x=f2bf(b3.x*scale); p3.y=f2bf(b3.y*scale); p3.z=f2bf(b3.z*scale); p3.w=f2bf(b3.w*scale);
        *(ushort4*)(bDst)      = p0;
        *(ushort4*)(bDst + 4)  = p1;
        *(ushort4*)(bDst + 8)  = p2;
        *(ushort4*)(bDst + 12) = p3;
        __syncthreads();
        shortx8 af[4], bfr[4];
        #pragma unroll
        for (int mt = 0; mt < 4; ++mt)
            af[mt] = *(const shortx8*)(As + (wm + mt * 16 + fr) * LDT + fq * 8);
        #pragma unroll
        for (int nt = 0; nt < 4; ++nt)
            bfr[nt] = *(const shortx8*)(Bs + (wn + nt * 16 + fr) * LDT + fq * 8);
        #pragma unroll
        for (int mt = 0; mt < 4; ++mt)
            #pragma unroll
            for (int nt = 0; nt < 4; ++nt)
                acc[mt][nt] = __builtin_amdgcn_mfma_f32_16x16x32_bf16(
                    af[mt], bfr[nt], acc[mt][nt], 0, 0, 0);
    }

    // epilogue: exp(64c - 64), reduce per row
    const float CLIPC = 0.99999950f;  // cos(0.001)
    int colbase = ctile * 128 + wn + fr;
    #pragma unroll
    for (int mt = 0; mt < 4; ++mt) {
        #pragma unroll
        for (int reg = 0; reg < 4; ++reg) {
            float s = 0.0f;
            #pragma unroll
            for (int nt = 0; nt < 4; ++nt) {
                int col = colbase + nt * 16;
                float c = acc[mt][nt][reg];
                c = fminf(fmaxf(c, -CLIPC), CLIPC);   // clip(cos) + theta clip combined
                float term = __expf(64.0f * c - 64.0f);
                s += (col < NCLS) ? term : 0.0f;
            }
            // reduce across the 16 lanes holding the same row (low 4 lane bits)
            s += __shfl_xor(s, 1); s += __shfl_xor(s, 2);
            s += __shfl_xor(s, 4); s += __shfl_xor(s, 8);
            if (fr == 0) atomicAdd(&red[wm + mt * 16 + fq * 4 + reg], s);
        }
    }
    __syncthreads();
    if (t < 128) atomicAdd(rowsum + mtile * 128 + t, red[t]);
}

// --- kernel 5: fp32-accurate cosine of the label column --------------------
__global__ __launch_bounds__(256) void coslab_kernel(
        const float* __restrict__ x, const float* __restrict__ W,
        const int* __restrict__ labels, const float* __restrict__ invn,
        const float* __restrict__ rownorm, float* __restrict__ coslab) {
    int wv = threadIdx.x >> 6, lane = threadIdx.x & 63;
    int r = blockIdx.x * 4 + wv;
    int lab = labels[r];
    const float4* xs = (const float4*)(x + r * DIM);
    const float4* ws = (const float4*)(W + (size_t)lab * DIM);
    float4 xa = xs[lane], xb = xs[lane + 64];
    float4 wa = ws[lane], wb = ws[lane + 64];
    float dot = xa.x*wa.x + xa.y*wa.y + xa.z*wa.z + xa.w*wa.w
              + xb.x*wb.x + xb.y*wb.y + xb.z*wb.z + xb.w*wb.w;
    dot = wave_reduce_sum(dot);
    if (lane == 0)
        coslab[r] = dot * (1.0f / fmaxf(rownorm[r], 1e-12f)) * invn[lab];
}

// --- kernel 6: margin correction + log + mean ------------------------------
__global__ __launch_bounds__(1024) void finalize_kernel(
        const float* __restrict__ rowsum, const float* __restrict__ coslab,
        const float* __restrict__ g_ang, const float* __restrict__ g_add,
        float* __restrict__ out) {
    __shared__ float sd[1024];
    int t = threadIdx.x;
    const float CLIPC = 0.99999950f;
    const float PI = 3.14159265358979323846f;
    float cl  = fminf(fmaxf(coslab[t], -1.0f), 1.0f);
    float cne = fminf(fmaxf(cl, -CLIPC), CLIPC);
    float logit_non = 64.0f * cne;                       // what the GEMM summed
    float theta = acosf(cl);
    float tm = fminf(fmaxf(theta + g_ang[t], 0.001f), PI - 0.001f);
    float logit_true = (__cosf(tm) - g_add[t]) * 64.0f;  // margin logit
    float ssum = rowsum[t] - __expf(logit_non - 64.0f) + __expf(logit_true - 64.0f);
    float loss = logf(ssum) + 64.0f - logit_true;        // lse - target logit
    sd[t] = loss; __syncthreads();
    for (int s = 512; s > 0; s >>= 1) { if (t < s) sd[t] += sd[t + s]; __syncthreads(); }
    if (t == 0) out[0] = sd[0] * (1.0f / 1024.0f);
}

extern "C" void kernel_launch(void* const* d_in, const int* in_sizes, int n_in,
                              void* d_out, int out_size, void* d_ws, size_t ws_size,
                              hipStream_t stream) {
    const float* x      = (const float*)d_in[0];
    const int*   labels = (const int*)d_in[1];
    const float* W      = (const float*)d_in[2];
    float* out = (float*)d_out;
    char* ws = (char*)d_ws;

    // workspace layout (~1.35 MB total)
    unsigned short* normx = (unsigned short*)ws;                   // 1024*512*2 = 1048576 B
    float* invn    = (float*)(ws + 1048576);                       // 70722*4 (padded to 283904)
    float* rownorm = (float*)(ws + 1048576 + 283904);
    float* g_ang   = rownorm + 1024;
    float* g_add   = g_ang + 1024;
    float* rowsum  = g_add + 1024;
    float* coslab  = rowsum + 1024;

    prep_x_kernel<<<NROWS / 4, 256, 0, stream>>>(x, normx, rownorm);
    stats_kernel<<<1, 1024, 0, stream>>>(rownorm, g_ang, g_add);
    prep_w_kernel<<<(NCLS + 3) / 4, 256, 0, stream>>>(W, invn);
    hipMemsetAsync(rowsum, 0, 1024 * sizeof(float), stream);
    dim3 grid(8, (NCLS + 127) / 128);   // mtile fastest -> W tile reuse in L2/L3
    gemm_kernel<<<grid, 256, 0, stream>>>(normx, W, invn, rowsum);
    coslab_kernel<<<NROWS / 4, 256, 0, stream>>>(x, W, labels, invn, rownorm, coslab);
    finalize_kernel<<<1, 1024, 0, stream>>>(rowsum, coslab, g_ang, g_add, out);
}

// Round 2
// 337.959 us; speedup vs baseline: 1.1577x; 1.1577x over previous
//
#include <hip/hip_runtime.h>
#include <hip/hip_bf16.h>
#include <stdint.h>

#define DIM 512
#define NROWS 1024
#define NCLS 70722
#define BK 32
#define LDT 40   // padded stride for fallback fp32-W gemm only

typedef float  floatx4 __attribute__((ext_vector_type(4)));
typedef short  shortx8 __attribute__((ext_vector_type(8)));

__device__ __forceinline__ unsigned short f2bf(float f) {
    union { float f; unsigned int u; } v; v.f = f;
    unsigned int r = v.u + 0x7FFFu + ((v.u >> 16) & 1u);  // RNE
    return (unsigned short)(r >> 16);
}

__device__ __forceinline__ float wave_reduce_sum(float s) {
    #pragma unroll
    for (int m = 1; m < 64; m <<= 1) s += __shfl_xor(s, m);
    return s;
}

// --- kernel 1: per-row x norms + normalized bf16 x -------------------------
__global__ __launch_bounds__(256) void prep_x_kernel(
        const float* __restrict__ x, unsigned short* __restrict__ normx,
        float* __restrict__ rownorm) {
    int wv = threadIdx.x >> 6, lane = threadIdx.x & 63;
    int row = blockIdx.x * 4 + wv;
    const float4* src = (const float4*)(x + row * DIM);
    float4 a = src[lane], b = src[lane + 64];
    float ss = a.x*a.x + a.y*a.y + a.z*a.z + a.w*a.w
             + b.x*b.x + b.y*b.y + b.z*b.z + b.w*b.w;
    ss = wave_reduce_sum(ss);
    float norm = sqrtf(ss);
    float inv  = 1.0f / fmaxf(norm, 1e-12f);
    ushort4 o0; o0.x = f2bf(a.x*inv); o0.y = f2bf(a.y*inv); o0.z = f2bf(a.z*inv); o0.w = f2bf(a.w*inv);
    ushort4 o1; o1.x = f2bf(b.x*inv); o1.y = f2bf(b.y*inv); o1.z = f2bf(b.z*inv); o1.w = f2bf(b.w*inv);
    ((ushort4*)(normx + row * DIM))[lane]      = o0;
    ((ushort4*)(normx + row * DIM))[lane + 64] = o1;
    if (lane == 0) rownorm[row] = norm;
}

// --- kernel 2: batch stats -> per-row margins ------------------------------
__global__ __launch_bounds__(1024) void stats_kernel(
        const float* __restrict__ rownorm,
        float* __restrict__ g_ang, float* __restrict__ g_add) {
    __shared__ float sd[1024];
    int t = threadIdx.x;
    float v = fminf(fmaxf(rownorm[t], 0.001f), 100.0f);   // safe_norms
    sd[t] = v; __syncthreads();
    for (int s = 512; s > 0; s >>= 1) { if (t < s) sd[t] += sd[t + s]; __syncthreads(); }
    float mean = sd[0] * (1.0f / 1024.0f);
    __syncthreads();
    float d = v - mean;
    sd[t] = d * d; __syncthreads();
    for (int s = 512; s > 0; s >>= 1) { if (t < s) sd[t] += sd[t + s]; __syncthreads(); }
    float stdv = sqrtf(sd[0] * (1.0f / 1023.0f));         // ddof=1
    float ms = d / (stdv + 0.001f) * 0.333f;
    ms = fminf(fmaxf(ms, -1.0f), 1.0f);
    g_ang[t] = -0.4f * ms;
    g_add[t] =  0.4f + 0.4f * ms;
}

// --- kernel 3 (new path): per-class 1/||w|| + normalized bf16 W ------------
__global__ __launch_bounds__(256) void prep_w_conv_kernel(
        const float* __restrict__ W, float* __restrict__ invn,
        unsigned short* __restrict__ Wn) {
    int wv = threadIdx.x >> 6, lane = threadIdx.x & 63;
    int c = blockIdx.x * 4 + wv;
    if (c >= NCLS) return;
    const float4* src = (const float4*)(W + (size_t)c * DIM);
    // lane's 8 contiguous elements (so the bf16 store is one uint4 per lane)
    float4 a = src[lane * 2], b = src[lane * 2 + 1];
    float ss = a.x*a.x + a.y*a.y + a.z*a.z + a.w*a.w
             + b.x*b.x + b.y*b.y + b.z*b.z + b.w*b.w;
    ss = wave_reduce_sum(ss);
    float inv = 1.0f / fmaxf(sqrtf(ss), 1e-12f);
    if (lane == 0) invn[c] = inv;
    union { unsigned short u[8]; uint4 v; } pk;
    pk.u[0] = f2bf(a.x*inv); pk.u[1] = f2bf(a.y*inv);
    pk.u[2] = f2bf(a.z*inv); pk.u[3] = f2bf(a.w*inv);
    pk.u[4] = f2bf(b.x*inv); pk.u[5] = f2bf(b.y*inv);
    pk.u[6] = f2bf(b.z*inv); pk.u[7] = f2bf(b.w*inv);
    ((uint4*)(Wn + (size_t)c * DIM))[lane] = pk.v;
}

// --- kernel 3 (fallback): per-class 1/||w|| only ---------------------------
__global__ __launch_bounds__(256) void prep_w_kernel(
        const float* __restrict__ W, float* __restrict__ invn) {
    int wv = threadIdx.x >> 6, lane = threadIdx.x & 63;
    int c = blockIdx.x * 4 + wv;
    if (c >= NCLS) return;
    const float4* src = (const float4*)(W + (size_t)c * DIM);
    float4 a = src[lane], b = src[lane + 64];
    float ss = a.x*a.x + a.y*a.y + a.z*a.z + a.w*a.w
             + b.x*b.x + b.y*b.y + b.z*b.z + b.w*b.w;
    ss = wave_reduce_sum(ss);
    if (lane == 0) invn[c] = 1.0f / fmaxf(sqrtf(ss), 1e-12f);
}

// --- kernel 4 (new path): bf16 GEMM w/ global_load_lds + fused sumexp ------
__global__ __launch_bounds__(256) void gemm2_kernel(
        const unsigned short* __restrict__ normx, const unsigned short* __restrict__ Wn,
        float* __restrict__ rowsum) {
    __shared__ unsigned short As[128 * BK];   // unpadded: global_load_lds layout
    __shared__ unsigned short Bs[128 * BK];
    __shared__ float red[128];
    int t = threadIdx.x, lane = t & 63, wv = t >> 6;
    int mtile = blockIdx.x, ctile = blockIdx.y;

    if (t < 128) red[t] = 0.0f;

    // staging: per wave-issue, 64 lanes cover 16 rows x 32 k (64 B/row).
    int srow  = wv * 16 + (lane >> 2);
    int skoff = (lane & 3) * 8;
    const unsigned short* aG = normx + (size_t)(mtile * 128 + srow) * DIM + skoff;
    int c0 = min(ctile * 128 + srow, NCLS - 1);
    int c1 = min(ctile * 128 + 64 + srow, NCLS - 1);
    const unsigned short* bG0 = Wn + (size_t)c0 * DIM + skoff;
    const unsigned short* bG1 = Wn + (size_t)c1 * DIM + skoff;
    unsigned short* aL = As + wv * 16 * BK;   // wave-uniform LDS base
    unsigned short* bL = Bs + wv * 16 * BK;

    floatx4 acc[4][4] = {};
    int wm = (wv >> 1) * 64, wn = (wv & 1) * 64;
    int fr = lane & 15, fq = lane >> 4;

    for (int kc = 0; kc < DIM; kc += BK) {
        __syncthreads();   // previous iter's frag reads done before overwrite
        __builtin_amdgcn_global_load_lds(
            (const __attribute__((address_space(1))) unsigned int*)(aG + kc),
            (__attribute__((address_space(3))) unsigned int*)(aL), 16, 0, 0);
        __builtin_amdgcn_global_load_lds(
            (const __attribute__((address_space(1))) unsigned int*)(aG + (size_t)64 * DIM + kc),
            (__attribute__((address_space(3))) unsigned int*)(aL + 64 * BK), 16, 0, 0);
        __builtin_amdgcn_global_load_lds(
            (const __attribute__((address_space(1))) unsigned int*)(bG0 + kc),
            (__attribute__((address_space(3))) unsigned int*)(bL), 16, 0, 0);
        __builtin_amdgcn_global_load_lds(
            (const __attribute__((address_space(1))) unsigned int*)(bG1 + kc),
            (__attribute__((address_space(3))) unsigned int*)(bL + 64 * BK), 16, 0, 0);
        __syncthreads();   // drains vmcnt -> LDS ready
        shortx8 af[4], bfr[4];
        #pragma unroll
        for (int mt = 0; mt < 4; ++mt)
            af[mt] = *(const shortx8*)(As + (wm + mt * 16 + fr) * BK + fq * 8);
        #pragma unroll
        for (int nt = 0; nt < 4; ++nt)
            bfr[nt] = *(const shortx8*)(Bs + (wn + nt * 16 + fr) * BK + fq * 8);
        #pragma unroll
        for (int mt = 0; mt < 4; ++mt)
            #pragma unroll
            for (int nt = 0; nt < 4; ++nt)
                acc[mt][nt] = __builtin_amdgcn_mfma_f32_16x16x32_bf16(
                    af[mt], bfr[nt], acc[mt][nt], 0, 0, 0);
    }

    // epilogue: exp(64c - 64), reduce per row
    const float CLIPC = 0.99999950f;  // cos(0.001)
    int colbase = ctile * 128 + wn + fr;
    #pragma unroll
    for (int mt = 0; mt < 4; ++mt) {
        #pragma unroll
        for (int reg = 0; reg < 4; ++reg) {
            float s = 0.0f;
            #pragma unroll
            for (int nt = 0; nt < 4; ++nt) {
                int col = colbase + nt * 16;
                float c = acc[mt][nt][reg];
                c = fminf(fmaxf(c, -CLIPC), CLIPC);
                float term = __expf(64.0f * c - 64.0f);
                s += (col < NCLS) ? term : 0.0f;
            }
            s += __shfl_xor(s, 1); s += __shfl_xor(s, 2);
            s += __shfl_xor(s, 4); s += __shfl_xor(s, 8);
            if (fr == 0) atomicAdd(&red[wm + mt * 16 + fq * 4 + reg], s);
        }
    }
    __syncthreads();
    if (t < 128) atomicAdd(rowsum + mtile * 128 + t, red[t]);
}

// --- kernel 4 (fallback): fp32-W GEMM with in-loop convert -----------------
__global__ __launch_bounds__(256) void gemm_kernel(
        const unsigned short* __restrict__ normx, const float* __restrict__ W,
        const float* __restrict__ invn, float* __restrict__ rowsum) {
    __shared__ unsigned short As[128 * LDT];
    __shared__ unsigned short Bs[128 * LDT];
    __shared__ float red[128];
    int t = threadIdx.x, lane = t & 63, wv = t >> 6;
    int mtile = blockIdx.x, ctile = blockIdx.y;

    int rowA = t >> 1, half = t & 1;
    const unsigned short* aSrc = normx + (mtile * 128 + rowA) * DIM + half * 16;
    int cls = min(ctile * 128 + rowA, NCLS - 1);
    const float* bSrc = W + (size_t)cls * DIM + half * 16;
    float scale = invn[cls];
    unsigned short* aDst = As + rowA * LDT + half * 16;
    unsigned short* bDst = Bs + rowA * LDT + half * 16;
    if (t < 128) red[t] = 0.0f;

    floatx4 acc[4][4] = {};
    int wm = (wv >> 1) * 64, wn = (wv & 1) * 64;
    int fr = lane & 15, fq = lane >> 4;

    for (int kc = 0; kc < DIM; kc += BK) {
        uint4  a0 = *(const uint4*)(aSrc + kc);
        uint4  a1 = *(const uint4*)(aSrc + kc + 8);
        float4 b0 = *(const float4*)(bSrc + kc);
        float4 b1 = *(const float4*)(bSrc + kc + 4);
        float4 b2 = *(const float4*)(bSrc + kc + 8);
        float4 b3 = *(const float4*)(bSrc + kc + 12);
        __syncthreads();
        *(uint4*)(aDst)     = a0;
        *(uint4*)(aDst + 8) = a1;
        ushort4 p0; p0.x=f2bf(b0.x*scale); p0.y=f2bf(b0.y*scale); p0.z=f2bf(b0.z*scale); p0.w=f2bf(b0.w*scale);
        ushort4 p1; p1.x=f2bf(b1.x*scale); p1.y=f2bf(b1.y*scale); p1.z=f2bf(b1.z*scale); p1.w=f2bf(b1.w*scale);
        ushort4 p2; p2.x=f2bf(b2.x*scale); p2.y=f2bf(b2.y*scale); p2.z=f2bf(b2.z*scale); p2.w=f2bf(b2.w*scale);
        ushort4 p3; p3.x=f2bf(b3.x*scale); p3.y=f2bf(b3.y*scale); p3.z=f2bf(b3.z*scale); p3.w=f2bf(b3.w*scale);
        *(ushort4*)(bDst)      = p0;
        *(ushort4*)(bDst + 4)  = p1;
        *(ushort4*)(bDst + 8)  = p2;
        *(ushort4*)(bDst + 12) = p3;
        __syncthreads();
        shortx8 af[4], bfr[4];
        #pragma unroll
        for (int mt = 0; mt < 4; ++mt)
            af[mt] = *(const shortx8*)(As + (wm + mt * 16 + fr) * LDT + fq * 8);
        #pragma unroll
        for (int nt = 0; nt < 4; ++nt)
            bfr[nt] = *(const shortx8*)(Bs + (wn + nt * 16 + fr) * LDT + fq * 8);
        #pragma unroll
        for (int mt = 0; mt < 4; ++mt)
            #pragma unroll
            for (int nt = 0; nt < 4; ++nt)
                acc[mt][nt] = __builtin_amdgcn_mfma_f32_16x16x32_bf16(
                    af[mt], bfr[nt], acc[mt][nt], 0, 0, 0);
    }

    const float CLIPC = 0.99999950f;
    int colbase = ctile * 128 + wn + fr;
    #pragma unroll
    for (int mt = 0; mt < 4; ++mt) {
        #pragma unroll
        for (int reg = 0; reg < 4; ++reg) {
            float s = 0.0f;
            #pragma unroll
            for (int nt = 0; nt < 4; ++nt) {
                int col = colbase + nt * 16;
                float c = acc[mt][nt][reg];
                c = fminf(fmaxf(c, -CLIPC), CLIPC);
                float term = __expf(64.0f * c - 64.0f);
                s += (col < NCLS) ? term : 0.0f;
            }
            s += __shfl_xor(s, 1); s += __shfl_xor(s, 2);
            s += __shfl_xor(s, 4); s += __shfl_xor(s, 8);
            if (fr == 0) atomicAdd(&red[wm + mt * 16 + fq * 4 + reg], s);
        }
    }
    __syncthreads();
    if (t < 128) atomicAdd(rowsum + mtile * 128 + t, red[t]);
}

// --- kernel 5: fp32-accurate cosine of the label column --------------------
__global__ __launch_bounds__(256) void coslab_kernel(
        const float* __restrict__ x, const float* __restrict__ W,
        const int* __restrict__ labels, const float* __restrict__ invn,
        const float* __restrict__ rownorm, float* __restrict__ coslab) {
    int wv = threadIdx.x >> 6, lane = threadIdx.x & 63;
    int r = blockIdx.x * 4 + wv;
    int lab = labels[r];
    const float4* xs = (const float4*)(x + r * DIM);
    const float4* ws = (const float4*)(W + (size_t)lab * DIM);
    float4 xa = xs[lane], xb = xs[lane + 64];
    float4 wa = ws[lane], wb = ws[lane + 64];
    float dot = xa.x*wa.x + xa.y*wa.y + xa.z*wa.z + xa.w*wa.w
              + xb.x*wb.x + xb.y*wb.y + xb.z*wb.z + xb.w*wb.w;
    dot = wave_reduce_sum(dot);
    if (lane == 0)
        coslab[r] = dot * (1.0f / fmaxf(rownorm[r], 1e-12f)) * invn[lab];
}

// --- kernel 6: margin correction + log + mean ------------------------------
__global__ __launch_bounds__(1024) void finalize_kernel(
        const float* __restrict__ rowsum, const float* __restrict__ coslab,
        const float* __restrict__ g_ang, const float* __restrict__ g_add,
        float* __restrict__ out) {
    __shared__ float sd[1024];
    int t = threadIdx.x;
    const float CLIPC = 0.99999950f;
    const float PI = 3.14159265358979323846f;
    float cl  = fminf(fmaxf(coslab[t], -1.0f), 1.0f);
    float cne = fminf(fmaxf(cl, -CLIPC), CLIPC);
    float logit_non = 64.0f * cne;
    float theta = acosf(cl);
    float tm = fminf(fmaxf(theta + g_ang[t], 0.001f), PI - 0.001f);
    float logit_true = (__cosf(tm) - g_add[t]) * 64.0f;
    float ssum = rowsum[t] - __expf(logit_non - 64.0f) + __expf(logit_true - 64.0f);
    float loss = logf(ssum) + 64.0f - logit_true;
    sd[t] = loss; __syncthreads();
    for (int s = 512; s > 0; s >>= 1) { if (t < s) sd[t] += sd[t + s]; __syncthreads(); }
    if (t == 0) out[0] = sd[0] * (1.0f / 1024.0f);
}

extern "C" void kernel_launch(void* const* d_in, const int* in_sizes, int n_in,
                              void* d_out, int out_size, void* d_ws, size_t ws_size,
                              hipStream_t stream) {
    const float* x      = (const float*)d_in[0];
    const int*   labels = (const int*)d_in[1];
    const float* W      = (const float*)d_in[2];
    float* out = (float*)d_out;
    char* ws = (char*)d_ws;

    const size_t SZ_NORMX = 1048576;                  // 1024*512*2
    const size_t SZ_WN    = 72419328;                 // 70722*512*2, 256-aligned
    const size_t SZ_INVN  = 283904;                   // 70722*4 padded

    if (ws_size >= SZ_NORMX + SZ_WN + SZ_INVN + 6 * 4096) {
        // ---- bf16-preconverted path ----
        unsigned short* normx = (unsigned short*)ws;
        unsigned short* Wn    = (unsigned short*)(ws + SZ_NORMX);
        float* invn    = (float*)(ws + SZ_NORMX + SZ_WN);
        float* rownorm = (float*)(ws + SZ_NORMX + SZ_WN + SZ_INVN);
        float* g_ang   = rownorm + 1024;
        float* g_add   = g_ang + 1024;
        float* rowsum  = g_add + 1024;
        float* coslab  = rowsum + 1024;

        prep_x_kernel<<<NROWS / 4, 256, 0, stream>>>(x, normx, rownorm);
        stats_kernel<<<1, 1024, 0, stream>>>(rownorm, g_ang, g_add);
        prep_w_conv_kernel<<<(NCLS + 3) / 4, 256, 0, stream>>>(W, invn, Wn);
        hipMemsetAsync(rowsum, 0, 1024 * sizeof(float), stream);
        dim3 grid(8, (NCLS + 127) / 128);   // mtile fastest
        gemm2_kernel<<<grid, 256, 0, stream>>>(normx, Wn, rowsum);
        coslab_kernel<<<NROWS / 4, 256, 0, stream>>>(x, W, labels, invn, rownorm, coslab);
        finalize_kernel<<<1, 1024, 0, stream>>>(rowsum, coslab, g_ang, g_add, out);
    } else {
        // ---- fallback: round-1 path ----
        unsigned short* normx = (unsigned short*)ws;
        float* invn    = (float*)(ws + 1048576);
        float* rownorm = (float*)(ws + 1048576 + 283904);
        float* g_ang   = rownorm + 1024;
        float* g_add   = g_ang + 1024;
        float* rowsum  = g_add + 1024;
        float* coslab  = rowsum + 1024;

        prep_x_kernel<<<NROWS / 4, 256, 0, stream>>>(x, normx, rownorm);
        stats_kernel<<<1, 1024, 0, stream>>>(rownorm, g_ang, g_add);
        prep_w_kernel<<<(NCLS + 3) / 4, 256, 0, stream>>>(W, invn);
        hipMemsetAsync(rowsum, 0, 1024 * sizeof(float), stream);
        dim3 grid(8, (NCLS + 127) / 128);
        gemm_kernel<<<grid, 256, 0, stream>>>(normx, W, invn, rowsum);
        coslab_kernel<<<NROWS / 4, 256, 0, stream>>>(x, W, labels, invn, rownorm, coslab);
        finalize_kernel<<<1, 1024, 0, stream>>>(rowsum, coslab, g_ang, g_add, out);
    }
}

// Round 3
// 322.349 us; speedup vs baseline: 1.2137x; 1.0484x over previous
//
#include <hip/hip_runtime.h>
#include <hip/hip_bf16.h>
#include <stdint.h>

#define DIM 512
#define NROWS 1024
#define NCLS 70722
#define BK 32
#define LDT 40         // padded stride for fallback fp32-W gemm only
#define NCTILE 553     // ceil(70722/128)

typedef float  floatx4 __attribute__((ext_vector_type(4)));
typedef short  shortx8 __attribute__((ext_vector_type(8)));

__device__ __forceinline__ unsigned short f2bf(float f) {
    union { float f; unsigned int u; } v; v.f = f;
    unsigned int r = v.u + 0x7FFFu + ((v.u >> 16) & 1u);  // RNE
    return (unsigned short)(r >> 16);
}

__device__ __forceinline__ float wave_reduce_sum(float s) {
    #pragma unroll
    for (int m = 1; m < 64; m <<= 1) s += __shfl_xor(s, m);
    return s;
}

// --- kernel 1: per-row x norms + normalized bf16 x + rowsum zero -----------
__global__ __launch_bounds__(256) void prep_x_kernel(
        const float* __restrict__ x, unsigned short* __restrict__ normx,
        float* __restrict__ rownorm, float* __restrict__ rowsum) {
    int wv = threadIdx.x >> 6, lane = threadIdx.x & 63;
    if (threadIdx.x < 4) rowsum[blockIdx.x * 4 + threadIdx.x] = 0.0f;
    int row = blockIdx.x * 4 + wv;
    const float4* src = (const float4*)(x + row * DIM);
    float4 a = src[lane], b = src[lane + 64];
    float ss = a.x*a.x + a.y*a.y + a.z*a.z + a.w*a.w
             + b.x*b.x + b.y*b.y + b.z*b.z + b.w*b.w;
    ss = wave_reduce_sum(ss);
    float norm = sqrtf(ss);
    float inv  = 1.0f / fmaxf(norm, 1e-12f);
    ushort4 o0; o0.x = f2bf(a.x*inv); o0.y = f2bf(a.y*inv); o0.z = f2bf(a.z*inv); o0.w = f2bf(a.w*inv);
    ushort4 o1; o1.x = f2bf(b.x*inv); o1.y = f2bf(b.y*inv); o1.z = f2bf(b.z*inv); o1.w = f2bf(b.w*inv);
    ((ushort4*)(normx + row * DIM))[lane]      = o0;
    ((ushort4*)(normx + row * DIM))[lane + 64] = o1;
    if (lane == 0) rownorm[row] = norm;
}

// --- kernel 2: per-class 1/||w|| + normalized bf16 W -----------------------
__global__ __launch_bounds__(256) void prep_w_conv_kernel(
        const float* __restrict__ W, float* __restrict__ invn,
        unsigned short* __restrict__ Wn) {
    int wv = threadIdx.x >> 6, lane = threadIdx.x & 63;
    int c = blockIdx.x * 4 + wv;
    if (c >= NCLS) return;
    const float4* src = (const float4*)(W + (size_t)c * DIM);
    float4 a = src[lane * 2], b = src[lane * 2 + 1];
    float ss = a.x*a.x + a.y*a.y + a.z*a.z + a.w*a.w
             + b.x*b.x + b.y*b.y + b.z*b.z + b.w*b.w;
    ss = wave_reduce_sum(ss);
    float inv = 1.0f / fmaxf(sqrtf(ss), 1e-12f);
    if (lane == 0) invn[c] = inv;
    union { unsigned short u[8]; uint4 v; } pk;
    pk.u[0] = f2bf(a.x*inv); pk.u[1] = f2bf(a.y*inv);
    pk.u[2] = f2bf(a.z*inv); pk.u[3] = f2bf(a.w*inv);
    pk.u[4] = f2bf(b.x*inv); pk.u[5] = f2bf(b.y*inv);
    pk.u[6] = f2bf(b.z*inv); pk.u[7] = f2bf(b.w*inv);
    ((uint4*)(Wn + (size_t)c * DIM))[lane] = pk.v;
}

// --- kernel 2f (fallback): per-class 1/||w|| only --------------------------
__global__ __launch_bounds__(256) void prep_w_kernel(
        const float* __restrict__ W, float* __restrict__ invn) {
    int wv = threadIdx.x >> 6, lane = threadIdx.x & 63;
    int c = blockIdx.x * 4 + wv;
    if (c >= NCLS) return;
    const float4* src = (const float4*)(W + (size_t)c * DIM);
    float4 a = src[lane], b = src[lane + 64];
    float ss = a.x*a.x + a.y*a.y + a.z*a.z + a.w*a.w
             + b.x*b.x + b.y*b.y + b.z*b.z + b.w*b.w;
    ss = wave_reduce_sum(ss);
    if (lane == 0) invn[c] = 1.0f / fmaxf(sqrtf(ss), 1e-12f);
}

// --- kernel 3: self-contained fp32 cosine of the label column --------------
// (independent of all other kernels: computes both norms + dot itself)
__global__ __launch_bounds__(256) void coslab_kernel(
        const float* __restrict__ x, const float* __restrict__ W,
        const int* __restrict__ labels, float* __restrict__ coslab) {
    int wv = threadIdx.x >> 6, lane = threadIdx.x & 63;
    int r = blockIdx.x * 4 + wv;
    int lab = labels[r];
    const float4* xs = (const float4*)(x + r * DIM);
    const float4* ws = (const float4*)(W + (size_t)lab * DIM);
    float4 xa = xs[lane], xb = xs[lane + 64];
    float4 wa = ws[lane], wb = ws[lane + 64];
    float dxx = xa.x*xa.x + xa.y*xa.y + xa.z*xa.z + xa.w*xa.w
              + xb.x*xb.x + xb.y*xb.y + xb.z*xb.z + xb.w*xb.w;
    float dww = wa.x*wa.x + wa.y*wa.y + wa.z*wa.z + wa.w*wa.w
              + wb.x*wb.x + wb.y*wb.y + wb.z*wb.z + wb.w*wb.w;
    float dxw = xa.x*wa.x + xa.y*wa.y + xa.z*wa.z + xa.w*wa.w
              + xb.x*wb.x + xb.y*wb.y + xb.z*wb.z + xb.w*wb.w;
    dxx = wave_reduce_sum(dxx);
    dww = wave_reduce_sum(dww);
    dxw = wave_reduce_sum(dxw);
    if (lane == 0)
        coslab[r] = dxw / (fmaxf(sqrtf(dxx), 1e-12f) * fmaxf(sqrtf(dww), 1e-12f));
}

// --- kernel 4: bf16 GEMM (global_load_lds) + fused sumexp, XCD-swizzled ----
// Linear grid of 70*64 blocks. b%8 selects ctile%8 so all 8 mtile-blocks of
// one ctile share b%8 (-> same XCD under round-robin dispatch) for L2 reuse.
__global__ __launch_bounds__(256) void gemm2_kernel(
        const unsigned short* __restrict__ normx, const unsigned short* __restrict__ Wn,
        float* __restrict__ rowsum) {
    __shared__ unsigned short As[128 * BK];   // unpadded: global_load_lds layout
    __shared__ unsigned short Bs[128 * BK];
    __shared__ float red[128];
    int b = blockIdx.x;
    int ctile = (b >> 6) * 8 + (b & 7);
    int mtile = (b >> 3) & 7;
    if (ctile >= NCTILE) return;              // whole block exits together
    int t = threadIdx.x, lane = t & 63, wv = t >> 6;

    if (t < 128) red[t] = 0.0f;

    int srow  = wv * 16 + (lane >> 2);
    int skoff = (lane & 3) * 8;
    const unsigned short* aG = normx + (size_t)(mtile * 128 + srow) * DIM + skoff;
    int c0 = min(ctile * 128 + srow, NCLS - 1);
    int c1 = min(ctile * 128 + 64 + srow, NCLS - 1);
    const unsigned short* bG0 = Wn + (size_t)c0 * DIM + skoff;
    const unsigned short* bG1 = Wn + (size_t)c1 * DIM + skoff;
    unsigned short* aL = As + wv * 16 * BK;   // wave-uniform LDS base
    unsigned short* bL = Bs + wv * 16 * BK;

    floatx4 acc[4][4] = {};
    int wm = (wv >> 1) * 64, wn = (wv & 1) * 64;
    int fr = lane & 15, fq = lane >> 4;

    for (int kc = 0; kc < DIM; kc += BK) {
        __syncthreads();
        __builtin_amdgcn_global_load_lds(
            (const __attribute__((address_space(1))) unsigned int*)(aG + kc),
            (__attribute__((address_space(3))) unsigned int*)(aL), 16, 0, 0);
        __builtin_amdgcn_global_load_lds(
            (const __attribute__((address_space(1))) unsigned int*)(aG + (size_t)64 * DIM + kc),
            (__attribute__((address_space(3))) unsigned int*)(aL + 64 * BK), 16, 0, 0);
        __builtin_amdgcn_global_load_lds(
            (const __attribute__((address_space(1))) unsigned int*)(bG0 + kc),
            (__attribute__((address_space(3))) unsigned int*)(bL), 16, 0, 0);
        __builtin_amdgcn_global_load_lds(
            (const __attribute__((address_space(1))) unsigned int*)(bG1 + kc),
            (__attribute__((address_space(3))) unsigned int*)(bL + 64 * BK), 16, 0, 0);
        __syncthreads();
        shortx8 af[4], bfr[4];
        #pragma unroll
        for (int mt = 0; mt < 4; ++mt)
            af[mt] = *(const shortx8*)(As + (wm + mt * 16 + fr) * BK + fq * 8);
        #pragma unroll
        for (int nt = 0; nt < 4; ++nt)
            bfr[nt] = *(const shortx8*)(Bs + (wn + nt * 16 + fr) * BK + fq * 8);
        #pragma unroll
        for (int mt = 0; mt < 4; ++mt)
            #pragma unroll
            for (int nt = 0; nt < 4; ++nt)
                acc[mt][nt] = __builtin_amdgcn_mfma_f32_16x16x32_bf16(
                    af[mt], bfr[nt], acc[mt][nt], 0, 0, 0);
    }

    const float CLIPC = 0.99999950f;  // cos(0.001)
    int colbase = ctile * 128 + wn + fr;
    #pragma unroll
    for (int mt = 0; mt < 4; ++mt) {
        #pragma unroll
        for (int reg = 0; reg < 4; ++reg) {
            float s = 0.0f;
            #pragma unroll
            for (int nt = 0; nt < 4; ++nt) {
                int col = colbase + nt * 16;
                float c = acc[mt][nt][reg];
                c = fminf(fmaxf(c, -CLIPC), CLIPC);
                float term = __expf(64.0f * c - 64.0f);
                s += (col < NCLS) ? term : 0.0f;
            }
            s += __shfl_xor(s, 1); s += __shfl_xor(s, 2);
            s += __shfl_xor(s, 4); s += __shfl_xor(s, 8);
            if (fr == 0) atomicAdd(&red[wm + mt * 16 + fq * 4 + reg], s);
        }
    }
    __syncthreads();
    if (t < 128) atomicAdd(rowsum + mtile * 128 + t, red[t]);
}

// --- kernel 4f (fallback): fp32-W GEMM with in-loop convert ----------------
__global__ __launch_bounds__(256) void gemm_kernel(
        const unsigned short* __restrict__ normx, const float* __restrict__ W,
        const float* __restrict__ invn, float* __restrict__ rowsum) {
    __shared__ unsigned short As[128 * LDT];
    __shared__ unsigned short Bs[128 * LDT];
    __shared__ float red[128];
    int t = threadIdx.x, lane = t & 63, wv = t >> 6;
    int mtile = blockIdx.x, ctile = blockIdx.y;

    int rowA = t >> 1, half = t & 1;
    const unsigned short* aSrc = normx + (mtile * 128 + rowA) * DIM + half * 16;
    int cls = min(ctile * 128 + rowA, NCLS - 1);
    const float* bSrc = W + (size_t)cls * DIM + half * 16;
    float scale = invn[cls];
    unsigned short* aDst = As + rowA * LDT + half * 16;
    unsigned short* bDst = Bs + rowA * LDT + half * 16;
    if (t < 128) red[t] = 0.0f;

    floatx4 acc[4][4] = {};
    int wm = (wv >> 1) * 64, wn = (wv & 1) * 64;
    int fr = lane & 15, fq = lane >> 4;

    for (int kc = 0; kc < DIM; kc += BK) {
        uint4  a0 = *(const uint4*)(aSrc + kc);
        uint4  a1 = *(const uint4*)(aSrc + kc + 8);
        float4 b0 = *(const float4*)(bSrc + kc);
        float4 b1 = *(const float4*)(bSrc + kc + 4);
        float4 b2 = *(const float4*)(bSrc + kc + 8);
        float4 b3 = *(const float4*)(bSrc + kc + 12);
        __syncthreads();
        *(uint4*)(aDst)     = a0;
        *(uint4*)(aDst + 8) = a1;
        ushort4 p0; p0.x=f2bf(b0.x*scale); p0.y=f2bf(b0.y*scale); p0.z=f2bf(b0.z*scale); p0.w=f2bf(b0.w*scale);
        ushort4 p1; p1.x=f2bf(b1.x*scale); p1.y=f2bf(b1.y*scale); p1.z=f2bf(b1.z*scale); p1.w=f2bf(b1.w*scale);
        ushort4 p2; p2.x=f2bf(b2.x*scale); p2.y=f2bf(b2.y*scale); p2.z=f2bf(b2.z*scale); p2.w=f2bf(b2.w*scale);
        ushort4 p3; p3.x=f2bf(b3.x*scale); p3.y=f2bf(b3.y*scale); p3.z=f2bf(b3.z*scale); p3.w=f2bf(b3.w*scale);
        *(ushort4*)(bDst)      = p0;
        *(ushort4*)(bDst + 4)  = p1;
        *(ushort4*)(bDst + 8)  = p2;
        *(ushort4*)(bDst + 12) = p3;
        __syncthreads();
        shortx8 af[4], bfr[4];
        #pragma unroll
        for (int mt = 0; mt < 4; ++mt)
            af[mt] = *(const shortx8*)(As + (wm + mt * 16 + fr) * LDT + fq * 8);
        #pragma unroll
        for (int nt = 0; nt < 4; ++nt)
            bfr[nt] = *(const shortx8*)(Bs + (wn + nt * 16 + fr) * LDT + fq * 8);
        #pragma unroll
        for (int mt = 0; mt < 4; ++mt)
            #pragma unroll
            for (int nt = 0; nt < 4; ++nt)
                acc[mt][nt] = __builtin_amdgcn_mfma_f32_16x16x32_bf16(
                    af[mt], bfr[nt], acc[mt][nt], 0, 0, 0);
    }

    const float CLIPC = 0.99999950f;
    int colbase = ctile * 128 + wn + fr;
    #pragma unroll
    for (int mt = 0; mt < 4; ++mt) {
        #pragma unroll
        for (int reg = 0; reg < 4; ++reg) {
            float s = 0.0f;
            #pragma unroll
            for (int nt = 0; nt < 4; ++nt) {
                int col = colbase + nt * 16;
                float c = acc[mt][nt][reg];
                c = fminf(fmaxf(c, -CLIPC), CLIPC);
                float term = __expf(64.0f * c - 64.0f);
                s += (col < NCLS) ? term : 0.0f;
            }
            s += __shfl_xor(s, 1); s += __shfl_xor(s, 2);
            s += __shfl_xor(s, 4); s += __shfl_xor(s, 8);
            if (fr == 0) atomicAdd(&red[wm + mt * 16 + fq * 4 + reg], s);
        }
    }
    __syncthreads();
    if (t < 128) atomicAdd(rowsum + mtile * 128 + t, red[t]);
}

// --- kernel 5: fused batch-stats + margin correction + log + mean ----------
__global__ __launch_bounds__(1024) void finalize_kernel(
        const float* __restrict__ rowsum, const float* __restrict__ coslab,
        const float* __restrict__ rownorm, float* __restrict__ out) {
    __shared__ float sd[1024];
    int t = threadIdx.x;
    // batch stats on safe_norms (= clip(||x||, 0.001, 100))
    float v = fminf(fmaxf(rownorm[t], 0.001f), 100.0f);
    sd[t] = v; __syncthreads();
    for (int s = 512; s > 0; s >>= 1) { if (t < s) sd[t] += sd[t + s]; __syncthreads(); }
    float mean = sd[0] * (1.0f / 1024.0f);
    __syncthreads();
    float d = v - mean;
    sd[t] = d * d; __syncthreads();
    for (int s = 512; s > 0; s >>= 1) { if (t < s) sd[t] += sd[t + s]; __syncthreads(); }
    float stdv = sqrtf(sd[0] * (1.0f / 1023.0f));         // ddof=1
    float ms = d / (stdv + 0.001f) * 0.333f;
    ms = fminf(fmaxf(ms, -1.0f), 1.0f);
    float g_ang = -0.4f * ms;
    float g_add =  0.4f + 0.4f * ms;
    // label-column margin correction
    const float CLIPC = 0.99999950f;
    const float PI = 3.14159265358979323846f;
    float cl  = fminf(fmaxf(coslab[t], -1.0f), 1.0f);
    float cne = fminf(fmaxf(cl, -CLIPC), CLIPC);
    float logit_non = 64.0f * cne;                        // what the GEMM summed
    float theta = acosf(cl);
    float tm = fminf(fmaxf(theta + g_ang, 0.001f), PI - 0.001f);
    float logit_true = (__cosf(tm) - g_add) * 64.0f;
    float ssum = rowsum[t] - __expf(logit_non - 64.0f) + __expf(logit_true - 64.0f);
    float loss = logf(ssum) + 64.0f - logit_true;
    __syncthreads();
    sd[t] = loss; __syncthreads();
    for (int s = 512; s > 0; s >>= 1) { if (t < s) sd[t] += sd[t + s]; __syncthreads(); }
    if (t == 0) out[0] = sd[0] * (1.0f / 1024.0f);
}

extern "C" void kernel_launch(void* const* d_in, const int* in_sizes, int n_in,
                              void* d_out, int out_size, void* d_ws, size_t ws_size,
                              hipStream_t stream) {
    const float* x      = (const float*)d_in[0];
    const int*   labels = (const int*)d_in[1];
    const float* W      = (const float*)d_in[2];
    float* out = (float*)d_out;
    char* ws = (char*)d_ws;

    const size_t SZ_NORMX = 1048576;                  // 1024*512*2
    const size_t SZ_WN    = 72419328;                 // 70722*512*2, 256-aligned
    const size_t SZ_INVN  = 283904;                   // 70722*4 padded

    if (ws_size >= SZ_NORMX + SZ_WN + SZ_INVN + 6 * 4096) {
        // ---- bf16-preconverted path ----
        unsigned short* normx = (unsigned short*)ws;
        unsigned short* Wn    = (unsigned short*)(ws + SZ_NORMX);
        float* invn    = (float*)(ws + SZ_NORMX + SZ_WN);
        float* rownorm = (float*)(ws + SZ_NORMX + SZ_WN + SZ_INVN);
        float* rowsum  = rownorm + 1024;
        float* coslab  = rowsum + 1024;

        prep_x_kernel<<<NROWS / 4, 256, 0, stream>>>(x, normx, rownorm, rowsum);
        prep_w_conv_kernel<<<(NCLS + 3) / 4, 256, 0, stream>>>(W, invn, Wn);
        coslab_kernel<<<NROWS / 4, 256, 0, stream>>>(x, W, labels, coslab);
        gemm2_kernel<<<70 * 64, 256, 0, stream>>>(normx, Wn, rowsum);
        finalize_kernel<<<1, 1024, 0, stream>>>(rowsum, coslab, rownorm, out);
    } else {
        // ---- fallback: fp32-W path ----
        unsigned short* normx = (unsigned short*)ws;
        float* invn    = (float*)(ws + 1048576);
        float* rownorm = (float*)(ws + 1048576 + 283904);
        float* rowsum  = rownorm + 1024;
        float* coslab  = rowsum + 1024;

        prep_x_kernel<<<NROWS / 4, 256, 0, stream>>>(x, normx, rownorm, rowsum);
        prep_w_kernel<<<(NCLS + 3) / 4, 256, 0, stream>>>(W, invn);
        coslab_kernel<<<NROWS / 4, 256, 0, stream>>>(x, W, labels, coslab);
        dim3 grid(8, NCTILE);
        gemm_kernel<<<grid, 256, 0, stream>>>(normx, W, invn, rowsum);
        finalize_kernel<<<1, 1024, 0, stream>>>(rowsum, coslab, rownorm, out);
    }
}